// Round 3
// baseline (58.463 us; speedup 1.0000x reference)
//
#include <hip/hip_runtime.h>

// Elementwise fused forward:
//   act = sigmoid(x*cw + cb)
//   h   = relu(act*w1 + b1); h = relu(h*w2 + b2)
//   out = 0.5*(sigmoid(h*w30 + b30) + sigmoid(h*w31 + b31))
//
// Memory-bound streaming. R1 lessons:
//  - input (128 MiB) is partially L3-resident across replays; output writes
//    were evicting it -> use NON-TEMPORAL stores for the pure output stream.
//  - 16-iter grid-stride loop cost VALU issue slots -> 4x float4 per thread,
//    loop-free, 4 independent loads in flight (ILP).
// R2 fix: __builtin_nontemporal_store needs a native vector type, not
// HIP_vector_type<float,4> -> use ext_vector_type(4).

typedef float f32x4 __attribute__((ext_vector_type(4)));

__device__ __forceinline__ float fast_sigmoid(float x) {
    return 1.0f / (1.0f + __expf(-x));
}

__global__ __launch_bounds__(256) void hybridconv_kernel(
    const f32x4* __restrict__ data4,
    f32x4* __restrict__ out4,
    const float* __restrict__ cw_p, const float* __restrict__ cb_p,
    const float* __restrict__ w1_p, const float* __restrict__ b1_p,
    const float* __restrict__ w2_p, const float* __restrict__ b2_p,
    const float* __restrict__ w3_p, const float* __restrict__ b3_p,
    int n4)
{
    const float cw  = *cw_p,   cb  = *cb_p;
    const float w1  = *w1_p,   b1  = *b1_p;
    const float w2  = *w2_p,   b2  = *b2_p;
    const float w30 = w3_p[0], w31 = w3_p[1];
    const float b30 = b3_p[0], b31 = b3_p[1];

    // Each block covers 4*256 float4s; lanes stay coalesced within each chunk.
    const int base = blockIdx.x * (blockDim.x * 4) + threadIdx.x;

    f32x4 v[4];
    int idx[4];
#pragma unroll
    for (int k = 0; k < 4; ++k) {
        idx[k] = base + k * 256;
        if (idx[k] < n4) v[k] = data4[idx[k]];
    }

#pragma unroll
    for (int k = 0; k < 4; ++k) {
        if (idx[k] >= n4) continue;
        f32x4 r;
#pragma unroll
        for (int j = 0; j < 4; ++j) {
            float act = fast_sigmoid(fmaf(v[k][j], cw, cb));
            float h   = fmaxf(fmaf(act, w1, b1), 0.0f);
            h         = fmaxf(fmaf(h,   w2, b2), 0.0f);
            float s0  = fast_sigmoid(fmaf(h, w30, b30));
            float s1  = fast_sigmoid(fmaf(h, w31, b31));
            r[j] = 0.5f * (s0 + s1);
        }
        // Non-temporal: don't let the output stream evict the L3-resident input.
        __builtin_nontemporal_store(r, &out4[idx[k]]);
    }
}

extern "C" void kernel_launch(void* const* d_in, const int* in_sizes, int n_in,
                              void* d_out, int out_size, void* d_ws, size_t ws_size,
                              hipStream_t stream) {
    const float* data = (const float*)d_in[0];
    const float* cw   = (const float*)d_in[1];
    const float* cb   = (const float*)d_in[2];
    const float* w1   = (const float*)d_in[3];
    const float* b1   = (const float*)d_in[4];
    const float* w2   = (const float*)d_in[5];
    const float* b2   = (const float*)d_in[6];
    const float* w3   = (const float*)d_in[7];
    const float* b3   = (const float*)d_in[8];
    float* out = (float*)d_out;

    const int n  = in_sizes[0];       // 33,554,432
    const int n4 = n / 4;             // 8,388,608 float4s

    const int block = 256;
    const int per_block = block * 4;  // 1024 float4s per block
    const int grid = (n4 + per_block - 1) / per_block;   // 8192

    hybridconv_kernel<<<grid, block, 0, stream>>>(
        (const f32x4*)data, (f32x4*)out,
        cw, cb, w1, b1, w2, b2, w3, b3, n4);
}

// Round 4
// 50.558 us; speedup vs baseline: 1.1564x; 1.1564x over previous
//
#include <hip/hip_runtime.h>
#include <math.h>

// out(x) = 0.5*(sigmoid(h*w30+b30) + sigmoid(h*w31+b31))
//   h   = relu(relu(sigmoid(x*cw+cb)*w1 + b1)*w2 + b2)
//
// R3 post-mortem: VALU/trans pipe (6 transcendentals/elem) co-limits with HBM
// at ~60%/~56%. Replace the whole scalar function with a piecewise-linear LUT
// over t = x*cw+cb clamped to [-12,12] (sigma saturates beyond; downstream
// error <1e-5). 2048 intervals -> lerp error ~1e-4 << 3.65e-3 threshold.
// Table built once by a 1-block kernel (accurate expf) into d_ws, then staged
// global->LDS per block. Hot loop: 1 fma + clamp + cvt + fract + 2 LDS reads
// + 1 sub + 1 fma per element.

typedef float f32x4 __attribute__((ext_vector_type(4)));

#define TBL_N     2048            // intervals
#define TBL_NODES (TBL_N + 1)     // 2049 node values
#define TBL_LO    (-12.0f)
#define TBL_SCALE (TBL_N / 24.0f) // intervals per unit t

__global__ __launch_bounds__(256) void build_table_kernel(
    float* __restrict__ tbl,
    const float* __restrict__ cw_p, const float* __restrict__ cb_p,  // unused; domain is t
    const float* __restrict__ w1_p, const float* __restrict__ b1_p,
    const float* __restrict__ w2_p, const float* __restrict__ b2_p,
    const float* __restrict__ w3_p, const float* __restrict__ b3_p)
{
    const float w1  = *w1_p,   b1  = *b1_p;
    const float w2  = *w2_p,   b2  = *b2_p;
    const float w30 = w3_p[0], w31 = w3_p[1];
    const float b30 = b3_p[0], b31 = b3_p[1];

    for (int i = threadIdx.x; i < TBL_NODES; i += blockDim.x) {
        float t   = TBL_LO + (float)i * (1.0f / TBL_SCALE);
        float act = 1.0f / (1.0f + expf(-t));            // accurate expf here
        float h   = fmaxf(fmaf(act, w1, b1), 0.0f);
        h         = fmaxf(fmaf(h,   w2, b2), 0.0f);
        float s0  = 1.0f / (1.0f + expf(-fmaf(h, w30, b30)));
        float s1  = 1.0f / (1.0f + expf(-fmaf(h, w31, b31)));
        tbl[i] = 0.5f * (s0 + s1);
    }
}

__global__ __launch_bounds__(256) void hybridconv_lut_kernel(
    const f32x4* __restrict__ data4,
    f32x4* __restrict__ out4,
    const float* __restrict__ tbl,
    const float* __restrict__ cw_p, const float* __restrict__ cb_p,
    int n4)
{
    __shared__ float lut[TBL_NODES];

    // Stage table global->LDS: 512 float4 = 2048 floats + 1 tail.
    {
        const f32x4* t4 = (const f32x4*)tbl;
        f32x4* l4 = (f32x4*)lut;
        l4[threadIdx.x]       = t4[threadIdx.x];
        l4[threadIdx.x + 256] = t4[threadIdx.x + 256];
        if (threadIdx.x == 0) lut[TBL_N] = tbl[TBL_N];
    }
    __syncthreads();

    // u = (x*cw + cb - LO) * SCALE, folded into one fma.
    const float A = (*cw_p) * TBL_SCALE;
    const float B = ((*cb_p) - TBL_LO) * TBL_SCALE;
    const float UMAX = (float)TBL_N - 0.001f;

    // 2048 blocks * 256 threads * 16 f4 = 8,388,608 f4 = n4.
    const int base = blockIdx.x * (256 * 16) + threadIdx.x;

#pragma unroll
    for (int kk = 0; kk < 4; ++kk) {
        f32x4 v[4];
        int idx[4];
#pragma unroll
        for (int k = 0; k < 4; ++k) {
            idx[k] = base + (kk * 4 + k) * 256;
            if (idx[k] < n4) v[k] = data4[idx[k]];
        }
#pragma unroll
        for (int k = 0; k < 4; ++k) {
            if (idx[k] >= n4) continue;
            f32x4 r;
#pragma unroll
            for (int j = 0; j < 4; ++j) {
                float u = fmaf(v[k][j], A, B);
                u = fminf(fmaxf(u, 0.0f), UMAX);   // v_med3 clamp
                int   i  = (int)u;                  // trunc == floor (u>=0)
                float fr = u - (float)i;
                float f0 = lut[i];
                float f1 = lut[i + 1];
                r[j] = fmaf(fr, f1 - f0, f0);
            }
            __builtin_nontemporal_store(r, &out4[idx[k]]);
        }
    }
}

extern "C" void kernel_launch(void* const* d_in, const int* in_sizes, int n_in,
                              void* d_out, int out_size, void* d_ws, size_t ws_size,
                              hipStream_t stream) {
    const float* data = (const float*)d_in[0];
    const float* cw   = (const float*)d_in[1];
    const float* cb   = (const float*)d_in[2];
    const float* w1   = (const float*)d_in[3];
    const float* b1   = (const float*)d_in[4];
    const float* w2   = (const float*)d_in[5];
    const float* b2   = (const float*)d_in[6];
    const float* w3   = (const float*)d_in[7];
    const float* b3   = (const float*)d_in[8];
    float* out = (float*)d_out;
    float* tbl = (float*)d_ws;        // 2049 floats = 8.2 KB scratch

    const int n  = in_sizes[0];       // 33,554,432
    const int n4 = n / 4;             // 8,388,608 float4s

    build_table_kernel<<<1, 256, 0, stream>>>(tbl, cw, cb, w1, b1, w2, b2, w3, b3);

    const int block = 256;
    const int per_block = block * 16;                 // 4096 float4s per block
    const int grid = (n4 + per_block - 1) / per_block; // 2048
    hybridconv_lut_kernel<<<grid, block, 0, stream>>>(
        (const f32x4*)data, (f32x4*)out, tbl, cw, cb, n4);
}

// Round 5
// 48.733 us; speedup vs baseline: 1.1997x; 1.0375x over previous
//
#include <hip/hip_runtime.h>
#include <math.h>

// out(x) = 0.5*(sigmoid(h*w30+b30) + sigmoid(h*w31+b31))
//   h   = relu(relu(sigmoid(x*cw+cb)*w1 + b1)*w2 + b2)
//
// Scalar function of t = x*cw+cb, saturating outside [-12,12] ->
// piecewise-linear LUT (2048 intervals, lerp err ~4e-4 << 3.65e-3 thr).
//
// R4 post-mortem: 50.6us. Two residual costs:
//  1. separate 1-block builder kernel serialized in the graph (~4us/replay)
//  2. 5.0M LDS bank-conflict cycles from TWO random b32 gathers per element
// R5: fuse table build into each block (16 expf-node evals/thread, amortized
// over 16K elements/block) and store (f0,f1) PAIRS -> ONE ds_read_b64/elem.

typedef float  f32x4 __attribute__((ext_vector_type(4)));
typedef float  f32x2 __attribute__((ext_vector_type(2)));

#define TBL_N     2048            // intervals (pairs)
#define TBL_LO    (-12.0f)
#define TBL_STEP  (24.0f / TBL_N)
#define TBL_SCALE (TBL_N / 24.0f)

__device__ __forceinline__ float net_eval(float t, float w1, float b1,
                                          float w2, float b2,
                                          float w30, float b30,
                                          float w31, float b31) {
    float act = 1.0f / (1.0f + expf(-t));          // accurate expf (build only)
    float h   = fmaxf(fmaf(act, w1, b1), 0.0f);
    h         = fmaxf(fmaf(h,   w2, b2), 0.0f);
    float s0  = 1.0f / (1.0f + expf(-fmaf(h, w30, b30)));
    float s1  = 1.0f / (1.0f + expf(-fmaf(h, w31, b31)));
    return 0.5f * (s0 + s1);
}

__global__ __launch_bounds__(256) void hybridconv_lut_kernel(
    const f32x4* __restrict__ data4,
    f32x4* __restrict__ out4,
    const float* __restrict__ cw_p, const float* __restrict__ cb_p,
    const float* __restrict__ w1_p, const float* __restrict__ b1_p,
    const float* __restrict__ w2_p, const float* __restrict__ b2_p,
    const float* __restrict__ w3_p, const float* __restrict__ b3_p,
    int n4)
{
    __shared__ f32x2 lut[TBL_N];   // (f(t_i), f(t_{i+1})) pairs, 16 KB

    {
        const float w1  = *w1_p,   b1  = *b1_p;
        const float w2  = *w2_p,   b2  = *b2_p;
        const float w30 = w3_p[0], w31 = w3_p[1];
        const float b30 = b3_p[0], b31 = b3_p[1];
        // 2048 pairs / 256 threads = 8 pairs (16 node evals) per thread.
        for (int i = threadIdx.x; i < TBL_N; i += 256) {
            float t0 = TBL_LO + (float)i * TBL_STEP;
            float f0 = net_eval(t0,            w1, b1, w2, b2, w30, b30, w31, b31);
            float f1 = net_eval(t0 + TBL_STEP, w1, b1, w2, b2, w30, b30, w31, b31);
            f32x2 p; p.x = f0; p.y = f1;
            lut[i] = p;
        }
    }
    __syncthreads();

    // u = (x*cw + cb - LO) * SCALE in one fma.
    const float A = (*cw_p) * TBL_SCALE;
    const float B = ((*cb_p) - TBL_LO) * TBL_SCALE;
    const float UMAX = (float)TBL_N - 0.001f;

    // 2048 blocks * 256 threads * 16 f4 = 8,388,608 f4 = n4 exactly.
    const int base = blockIdx.x * (256 * 16) + threadIdx.x;

#pragma unroll
    for (int kk = 0; kk < 4; ++kk) {
        f32x4 v[4];
        int idx[4];
#pragma unroll
        for (int k = 0; k < 4; ++k) {
            idx[k] = base + (kk * 4 + k) * 256;
            if (idx[k] < n4) v[k] = data4[idx[k]];
        }
#pragma unroll
        for (int k = 0; k < 4; ++k) {
            if (idx[k] >= n4) continue;
            f32x4 r;
#pragma unroll
            for (int j = 0; j < 4; ++j) {
                float u = fmaf(v[k][j], A, B);
                u = fminf(fmaxf(u, 0.0f), UMAX);    // v_med3 clamp
                int   i  = (int)u;
                float fr = u - (float)i;
                f32x2 p  = lut[i];                  // one ds_read_b64
                r[j] = fmaf(fr, p.y - p.x, p.x);
            }
            __builtin_nontemporal_store(r, &out4[idx[k]]);
        }
    }
}

extern "C" void kernel_launch(void* const* d_in, const int* in_sizes, int n_in,
                              void* d_out, int out_size, void* d_ws, size_t ws_size,
                              hipStream_t stream) {
    const float* data = (const float*)d_in[0];
    const float* cw   = (const float*)d_in[1];
    const float* cb   = (const float*)d_in[2];
    const float* w1   = (const float*)d_in[3];
    const float* b1   = (const float*)d_in[4];
    const float* w2   = (const float*)d_in[5];
    const float* b2   = (const float*)d_in[6];
    const float* w3   = (const float*)d_in[7];
    const float* b3   = (const float*)d_in[8];
    float* out = (float*)d_out;

    const int n  = in_sizes[0];       // 33,554,432
    const int n4 = n / 4;             // 8,388,608 float4s

    const int block = 256;
    const int per_block = block * 16;                  // 4096 float4s per block
    const int grid = (n4 + per_block - 1) / per_block; // 2048 (= 8 blocks/CU)

    hybridconv_lut_kernel<<<grid, block, 0, stream>>>(
        (const f32x4*)data, (f32x4*)out,
        cw, cb, w1, b1, w2, b2, w3, b3, n4);
}

// Round 6
// 47.142 us; speedup vs baseline: 1.2401x; 1.0337x over previous
//
#include <hip/hip_runtime.h>
#include <math.h>

// out(x) = f(t), t = x*cw+cb; f = 0.5*(sig(h*w30+b30)+sig(h*w31+b31)),
//   h = relu(relu(sig(t)*w1+b1)*w2+b2).  Piecewise-linear LUT on t in [-12,12].
//
// R5 post-mortem: 48.7us, VALUBusy 31% -- per-block table build (16 libm-expf
// evals/thread x 2048 blocks) became the co-limiter. R6: cut build work ~12x:
//   1. __expf (v_exp_f32) instead of libm expf        (~5x fewer VALU ops)
//   2. build 2049 NODES then pair-ify via LDS copy    (2x fewer evals)
//   3. grid 1024, 32 f4/thread                        (2x fewer builds total)
// Gather stays f32-pair ds_read_b64 (one LDS inst/elem).

typedef float f32x4 __attribute__((ext_vector_type(4)));
typedef float f32x2 __attribute__((ext_vector_type(2)));

#define TBL_N     2048            // intervals (pairs)
#define TBL_LO    (-12.0f)
#define TBL_STEP  (24.0f / TBL_N)
#define TBL_SCALE (TBL_N / 24.0f)

__device__ __forceinline__ float net_eval(float t, float w1, float b1,
                                          float w2, float b2,
                                          float w30, float b30,
                                          float w31, float b31) {
    float act = 1.0f / (1.0f + __expf(-t));        // v_exp_f32 + v_rcp_f32
    float h   = fmaxf(fmaf(act, w1, b1), 0.0f);
    h         = fmaxf(fmaf(h,   w2, b2), 0.0f);
    float s0  = 1.0f / (1.0f + __expf(-fmaf(h, w30, b30)));
    float s1  = 1.0f / (1.0f + __expf(-fmaf(h, w31, b31)));
    return 0.5f * (s0 + s1);
}

__global__ __launch_bounds__(256) void hybridconv_lut_kernel(
    const f32x4* __restrict__ data4,
    f32x4* __restrict__ out4,
    const float* __restrict__ cw_p, const float* __restrict__ cb_p,
    const float* __restrict__ w1_p, const float* __restrict__ b1_p,
    const float* __restrict__ w2_p, const float* __restrict__ b2_p,
    const float* __restrict__ w3_p, const float* __restrict__ b3_p,
    int n4)
{
    __shared__ f32x2 lut[TBL_N];   // (f(t_i), f(t_{i+1})) pairs, 16 KB
    __shared__ float node_last;    // f(t_2048)

    {
        const float w1  = *w1_p,   b1  = *b1_p;
        const float w2  = *w2_p,   b2  = *b2_p;
        const float w30 = w3_p[0], w31 = w3_p[1];
        const float b30 = b3_p[0], b31 = b3_p[1];
        // Pass 1: 2049 node evals total (8/thread), written into .x slots.
        for (int i = threadIdx.x; i < TBL_N; i += 256) {
            float t = TBL_LO + (float)i * TBL_STEP;
            lut[i].x = net_eval(t, w1, b1, w2, b2, w30, b30, w31, b31);
        }
        if (threadIdx.x == 0)
            node_last = net_eval(TBL_LO + (float)TBL_N * TBL_STEP,
                                 w1, b1, w2, b2, w30, b30, w31, b31);
    }
    __syncthreads();
    // Pass 2: pair-ify. Writes touch only .y words; reads touch .x words -> no race.
    for (int i = threadIdx.x; i < TBL_N; i += 256) {
        float nxt = (i == TBL_N - 1) ? node_last : lut[i + 1].x;
        lut[i].y = nxt;
    }
    __syncthreads();

    const float A = (*cw_p) * TBL_SCALE;
    const float B = ((*cb_p) - TBL_LO) * TBL_SCALE;
    const float UMAX = (float)TBL_N - 0.001f;

    // 1024 blocks * 256 threads * 32 f4 = 8,388,608 f4 = n4 exactly.
    const int base = blockIdx.x * (256 * 32) + threadIdx.x;

#pragma unroll
    for (int kk = 0; kk < 8; ++kk) {
        f32x4 v[4];
        int idx[4];
#pragma unroll
        for (int k = 0; k < 4; ++k) {
            idx[k] = base + (kk * 4 + k) * 256;
            if (idx[k] < n4) v[k] = data4[idx[k]];
        }
#pragma unroll
        for (int k = 0; k < 4; ++k) {
            if (idx[k] >= n4) continue;
            f32x4 r;
#pragma unroll
            for (int j = 0; j < 4; ++j) {
                float u = fmaf(v[k][j], A, B);
                u = fminf(fmaxf(u, 0.0f), UMAX);    // v_med3 clamp
                int   i  = (int)u;
                float fr = u - (float)i;
                f32x2 p  = lut[i];                  // one ds_read_b64
                r[j] = fmaf(fr, p.y - p.x, p.x);
            }
            __builtin_nontemporal_store(r, &out4[idx[k]]);
        }
    }
}

extern "C" void kernel_launch(void* const* d_in, const int* in_sizes, int n_in,
                              void* d_out, int out_size, void* d_ws, size_t ws_size,
                              hipStream_t stream) {
    const float* data = (const float*)d_in[0];
    const float* cw   = (const float*)d_in[1];
    const float* cb   = (const float*)d_in[2];
    const float* w1   = (const float*)d_in[3];
    const float* b1   = (const float*)d_in[4];
    const float* w2   = (const float*)d_in[5];
    const float* b2   = (const float*)d_in[6];
    const float* w3   = (const float*)d_in[7];
    const float* b3   = (const float*)d_in[8];
    float* out = (float*)d_out;

    const int n  = in_sizes[0];       // 33,554,432
    const int n4 = n / 4;             // 8,388,608 float4s

    const int block = 256;
    const int per_block = block * 32;                  // 8192 float4s per block
    const int grid = (n4 + per_block - 1) / per_block; // 1024 (= 4 blocks/CU)

    hybridconv_lut_kernel<<<grid, block, 0, stream>>>(
        (const f32x4*)data, (f32x4*)out,
        cw, cb, w1, b1, w2, b2, w3, b3, n4);
}

// Round 7
// 47.047 us; speedup vs baseline: 1.2427x; 1.0020x over previous
//
#include <hip/hip_runtime.h>
#include <math.h>

// out(x) = f(t), t = x*cw+cb; piecewise-linear LUT on t in [-12,12].
//
// R6 post-mortem: VALU 13% (build fixed) but occupancy 40% (1024 blocks) ->
// latency-bound; and f32-pair ds_read_b64 = stride-8B = only 16 bank-groups
// -> structural 4-way conflicts (2.6M cycles).
// R7: (1) grid 2048 (8 blocks/CU) for memory concurrency — build is cheap now;
//     (2) pack (f0,f1) as 2xf16 in one u32 -> ds_read_b32 stride 4B covers all
//         32 banks; random gather ~2 lanes/bank = free. f16 err 4.9e-4 +
//         lerp 4e-4 << 3.65e-3 threshold.

typedef float    f32x4 __attribute__((ext_vector_type(4)));
typedef _Float16 f16x2 __attribute__((ext_vector_type(2)));

#define TBL_N     2048            // intervals
#define TBL_NODES (TBL_N + 1)
#define TBL_LO    (-12.0f)
#define TBL_STEP  (24.0f / TBL_N)
#define TBL_SCALE (TBL_N / 24.0f)

__device__ __forceinline__ float net_eval(float t, float w1, float b1,
                                          float w2, float b2,
                                          float w30, float b30,
                                          float w31, float b31) {
    float act = 1.0f / (1.0f + __expf(-t));        // v_exp_f32 + v_rcp_f32
    float h   = fmaxf(fmaf(act, w1, b1), 0.0f);
    h         = fmaxf(fmaf(h,   w2, b2), 0.0f);
    float s0  = 1.0f / (1.0f + __expf(-fmaf(h, w30, b30)));
    float s1  = 1.0f / (1.0f + __expf(-fmaf(h, w31, b31)));
    return 0.5f * (s0 + s1);
}

__global__ __launch_bounds__(256) void hybridconv_lut_kernel(
    const f32x4* __restrict__ data4,
    f32x4* __restrict__ out4,
    const float* __restrict__ cw_p, const float* __restrict__ cb_p,
    const float* __restrict__ w1_p, const float* __restrict__ b1_p,
    const float* __restrict__ w2_p, const float* __restrict__ b2_p,
    const float* __restrict__ w3_p, const float* __restrict__ b3_p,
    int n4)
{
    __shared__ float    node[TBL_NODES];  // f32 node values (build scratch), 8.2 KB
    __shared__ unsigned lut[TBL_N];       // packed f16 (f0,f1) pairs, 8 KB

    {
        const float w1  = *w1_p,   b1  = *b1_p;
        const float w2  = *w2_p,   b2  = *b2_p;
        const float w30 = w3_p[0], w31 = w3_p[1];
        const float b30 = b3_p[0], b31 = b3_p[1];
        // Pass 1: 2049 node evals (8-9 per thread), fast __expf.
        for (int i = threadIdx.x; i < TBL_NODES; i += 256) {
            float t = TBL_LO + (float)i * TBL_STEP;
            node[i] = net_eval(t, w1, b1, w2, b2, w30, b30, w31, b31);
        }
    }
    __syncthreads();
    // Pass 2: pack (node[i], node[i+1]) as 2xf16 into one u32.
    for (int i = threadIdx.x; i < TBL_N; i += 256) {
        f16x2 p;
        p.x = (_Float16)node[i];
        p.y = (_Float16)node[i + 1];
        lut[i] = __builtin_bit_cast(unsigned, p);
    }
    __syncthreads();

    const float A = (*cw_p) * TBL_SCALE;
    const float B = ((*cb_p) - TBL_LO) * TBL_SCALE;
    const float UMAX = (float)TBL_N - 0.001f;

    // 2048 blocks * 256 threads * 16 f4 = 8,388,608 f4 = n4 exactly.
    const int base = blockIdx.x * (256 * 16) + threadIdx.x;

#pragma unroll
    for (int kk = 0; kk < 4; ++kk) {
        f32x4 v[4];
        int idx[4];
#pragma unroll
        for (int k = 0; k < 4; ++k) {
            idx[k] = base + (kk * 4 + k) * 256;
            if (idx[k] < n4) v[k] = data4[idx[k]];
        }
#pragma unroll
        for (int k = 0; k < 4; ++k) {
            if (idx[k] >= n4) continue;
            f32x4 r;
#pragma unroll
            for (int j = 0; j < 4; ++j) {
                float u = fmaf(v[k][j], A, B);
                u = fminf(fmaxf(u, 0.0f), UMAX);    // v_med3 clamp
                int   i  = (int)u;
                float fr = u - (float)i;
                f16x2 p  = __builtin_bit_cast(f16x2, lut[i]);  // one ds_read_b32
                float f0 = (float)p.x;
                float f1 = (float)p.y;
                r[j] = fmaf(fr, f1 - f0, f0);
            }
            __builtin_nontemporal_store(r, &out4[idx[k]]);
        }
    }
}

extern "C" void kernel_launch(void* const* d_in, const int* in_sizes, int n_in,
                              void* d_out, int out_size, void* d_ws, size_t ws_size,
                              hipStream_t stream) {
    const float* data = (const float*)d_in[0];
    const float* cw   = (const float*)d_in[1];
    const float* cb   = (const float*)d_in[2];
    const float* w1   = (const float*)d_in[3];
    const float* b1   = (const float*)d_in[4];
    const float* w2   = (const float*)d_in[5];
    const float* b2   = (const float*)d_in[6];
    const float* w3   = (const float*)d_in[7];
    const float* b3   = (const float*)d_in[8];
    float* out = (float*)d_out;

    const int n  = in_sizes[0];       // 33,554,432
    const int n4 = n / 4;             // 8,388,608 float4s

    const int block = 256;
    const int per_block = block * 16;                  // 4096 float4s per block
    const int grid = (n4 + per_block - 1) / per_block; // 2048 (= 8 blocks/CU)

    hybridconv_lut_kernel<<<grid, block, 0, stream>>>(
        (const f32x4*)data, (f32x4*)out,
        cw, cb, w1, b1, w2, b2, w3, b3, n4);
}

// Round 8
// 46.324 us; speedup vs baseline: 1.2621x; 1.0156x over previous
//
#include <hip/hip_runtime.h>

// out(x) = f(t), t = x*cw+cb; piecewise-linear f16-pair LUT on t in [-12,12].
//
// R7 post-mortem: 47us, occupancy 77%, VALU 18%, LDS conflicts negligible
// (2.5M cyc = ~0.075 cyc/gather -- mis-weighted in R5). At 70% of the 6.3TB/s
// mixed-stream ceiling. Remaining gap = scheduling overhead:
//  R8a: explicit double-buffered load pipeline (next 4 loads issue BEFORE the
//       gather-dependent stores of the current group; 8 loads in flight).
//  R8b: block-uniform full/tail branch -- hot path has NO per-lane bounds
//       guards (removes v_cmp+exec-mask around all 32 memory ops).
//  R8c: plain stores (nt provably didn't keep input L3-resident; fillBuffer
//       hits 6.9 TB/s with plain stores).

typedef float    f32x4 __attribute__((ext_vector_type(4)));
typedef _Float16 f16x2 __attribute__((ext_vector_type(2)));

#define TBL_N     2048            // intervals
#define TBL_NODES (TBL_N + 1)
#define TBL_LO    (-12.0f)
#define TBL_STEP  (24.0f / TBL_N)
#define TBL_SCALE (TBL_N / 24.0f)

__device__ __forceinline__ float net_eval(float t, float w1, float b1,
                                          float w2, float b2,
                                          float w30, float b30,
                                          float w31, float b31) {
    float act = 1.0f / (1.0f + __expf(-t));        // v_exp_f32 + v_rcp_f32
    float h   = fmaxf(fmaf(act, w1, b1), 0.0f);
    h         = fmaxf(fmaf(h,   w2, b2), 0.0f);
    float s0  = 1.0f / (1.0f + __expf(-fmaf(h, w30, b30)));
    float s1  = 1.0f / (1.0f + __expf(-fmaf(h, w31, b31)));
    return 0.5f * (s0 + s1);
}

__global__ __launch_bounds__(256) void hybridconv_lut_kernel(
    const f32x4* __restrict__ data4,
    f32x4* __restrict__ out4,
    const float* __restrict__ cw_p, const float* __restrict__ cb_p,
    const float* __restrict__ w1_p, const float* __restrict__ b1_p,
    const float* __restrict__ w2_p, const float* __restrict__ b2_p,
    const float* __restrict__ w3_p, const float* __restrict__ b3_p,
    int n4)
{
    __shared__ float    node[TBL_NODES];  // f32 nodes (build scratch), 8.2 KB
    __shared__ unsigned lut[TBL_N];       // packed f16 (f0,f1) pairs, 8 KB

    {
        const float w1  = *w1_p,   b1  = *b1_p;
        const float w2  = *w2_p,   b2  = *b2_p;
        const float w30 = w3_p[0], w31 = w3_p[1];
        const float b30 = b3_p[0], b31 = b3_p[1];
        for (int i = threadIdx.x; i < TBL_NODES; i += 256) {
            float t = TBL_LO + (float)i * TBL_STEP;
            node[i] = net_eval(t, w1, b1, w2, b2, w30, b30, w31, b31);
        }
    }
    __syncthreads();
    for (int i = threadIdx.x; i < TBL_N; i += 256) {
        f16x2 p;
        p.x = (_Float16)node[i];
        p.y = (_Float16)node[i + 1];
        lut[i] = __builtin_bit_cast(unsigned, p);
    }
    __syncthreads();

    const float A = (*cw_p) * TBL_SCALE;
    const float B = ((*cb_p) - TBL_LO) * TBL_SCALE;
    const float UMAX = (float)TBL_N - 0.001f;

    const int base = blockIdx.x * (256 * 16) + threadIdx.x;

#define LERP(dst, xin)                                                  \
    do {                                                                \
        float u = fmaf((xin), A, B);                                    \
        u = fminf(fmaxf(u, 0.0f), UMAX);                                \
        int   i_ = (int)u;                                              \
        float fr = u - (float)i_;                                       \
        f16x2 p_ = __builtin_bit_cast(f16x2, lut[i_]);                  \
        float f0 = (float)p_.x, f1 = (float)p_.y;                       \
        (dst) = fmaf(fr, f1 - f0, f0);                                  \
    } while (0)

    if ((blockIdx.x + 1) * (256 * 16) <= n4) {
        // ---- full block: no bounds checks, double-buffered pipeline ----
        f32x4 va[4], vb[4];
#pragma unroll
        for (int k = 0; k < 4; ++k) va[k] = data4[base + k * 256];

#pragma unroll
        for (int kk = 0; kk < 4; ++kk) {
            if (kk < 3) {
#pragma unroll
                for (int k = 0; k < 4; ++k)
                    vb[k] = data4[base + ((kk + 1) * 4 + k) * 256];
            }
#pragma unroll
            for (int k = 0; k < 4; ++k) {
                f32x4 r;
#pragma unroll
                for (int j = 0; j < 4; ++j) LERP(r[j], va[k][j]);
                out4[base + (kk * 4 + k) * 256] = r;
            }
#pragma unroll
            for (int k = 0; k < 4; ++k) va[k] = vb[k];
        }
    } else {
        // ---- tail block (not hit at N=33.5M): guarded ----
        for (int kk = 0; kk < 16; ++kk) {
            int idx = base + kk * 256;
            if (idx < n4) {
                f32x4 v = data4[idx];
                f32x4 r;
#pragma unroll
                for (int j = 0; j < 4; ++j) LERP(r[j], v[j]);
                out4[idx] = r;
            }
        }
    }
#undef LERP
}

extern "C" void kernel_launch(void* const* d_in, const int* in_sizes, int n_in,
                              void* d_out, int out_size, void* d_ws, size_t ws_size,
                              hipStream_t stream) {
    const float* data = (const float*)d_in[0];
    const float* cw   = (const float*)d_in[1];
    const float* cb   = (const float*)d_in[2];
    const float* w1   = (const float*)d_in[3];
    const float* b1   = (const float*)d_in[4];
    const float* w2   = (const float*)d_in[5];
    const float* b2   = (const float*)d_in[6];
    const float* w3   = (const float*)d_in[7];
    const float* b3   = (const float*)d_in[8];
    float* out = (float*)d_out;

    const int n  = in_sizes[0];       // 33,554,432
    const int n4 = n / 4;             // 8,388,608 float4s

    const int block = 256;
    const int per_block = block * 16;                  // 4096 float4s per block
    const int grid = (n4 + per_block - 1) / per_block; // 2048 (= 8 blocks/CU)

    hybridconv_lut_kernel<<<grid, block, 0, stream>>>(
        (const f32x4*)data, (f32x4*)out,
        cw, cb, w1, b1, w2, b2, w3, b3, n4);
}

// Round 9
// 44.356 us; speedup vs baseline: 1.3180x; 1.0444x over previous
//
#include <hip/hip_runtime.h>

// out(x) = f(t), t = x*cw+cb; piecewise-linear f16-pair LUT on t in [-12,12].
//
// R8 post-mortem: 46.3us = 5.8 TB/s LOGICAL stream rate (268.4 MB read+write)
// = 92% of the m13 float4-copy ceiling (6.29 TB/s -> 42.7us floor). HBM is at
// only 4.35 TB/s -> fabric-bound, not HBM-bound. Residual gap ~= the serial
// prologue: every wave does ~9 LUT node evals (6 quarter-rate trans ops each)
// + 2 barriers before its FIRST global load issues.
// R9: hoist group-0 loads ABOVE the table build (no LUT dependency) so the
// memory system streams during the build. Drop R8's explicit double-buffer
// (cost VGPR/occupancy, gained ~nothing). Keep guard-free full/tail split.

typedef float    f32x4 __attribute__((ext_vector_type(4)));
typedef _Float16 f16x2 __attribute__((ext_vector_type(2)));

#define TBL_N     2048            // intervals
#define TBL_NODES (TBL_N + 1)
#define TBL_LO    (-12.0f)
#define TBL_STEP  (24.0f / TBL_N)
#define TBL_SCALE (TBL_N / 24.0f)

__device__ __forceinline__ float net_eval(float t, float w1, float b1,
                                          float w2, float b2,
                                          float w30, float b30,
                                          float w31, float b31) {
    float act = 1.0f / (1.0f + __expf(-t));        // v_exp_f32 + v_rcp_f32
    float h   = fmaxf(fmaf(act, w1, b1), 0.0f);
    h         = fmaxf(fmaf(h,   w2, b2), 0.0f);
    float s0  = 1.0f / (1.0f + __expf(-fmaf(h, w30, b30)));
    float s1  = 1.0f / (1.0f + __expf(-fmaf(h, w31, b31)));
    return 0.5f * (s0 + s1);
}

__global__ __launch_bounds__(256) void hybridconv_lut_kernel(
    const f32x4* __restrict__ data4,
    f32x4* __restrict__ out4,
    const float* __restrict__ cw_p, const float* __restrict__ cb_p,
    const float* __restrict__ w1_p, const float* __restrict__ b1_p,
    const float* __restrict__ w2_p, const float* __restrict__ b2_p,
    const float* __restrict__ w3_p, const float* __restrict__ b3_p,
    int n4)
{
    __shared__ float    node[TBL_NODES];  // f32 nodes (build scratch), 8.2 KB
    __shared__ unsigned lut[TBL_N];       // packed f16 (f0,f1) pairs, 8 KB

    const int  base = blockIdx.x * (256 * 16) + threadIdx.x;
    const bool full = (blockIdx.x + 1) * (256 * 16) <= n4;

    // ---- hoisted group-0 loads: stream starts before/under the table build ----
    f32x4 v0[4];
#pragma unroll
    for (int k = 0; k < 4; ++k) {
        int idx = base + k * 256;
        if (full || idx < n4) v0[k] = data4[idx];
    }

    {
        const float w1  = *w1_p,   b1  = *b1_p;
        const float w2  = *w2_p,   b2  = *b2_p;
        const float w30 = w3_p[0], w31 = w3_p[1];
        const float b30 = b3_p[0], b31 = b3_p[1];
        for (int i = threadIdx.x; i < TBL_NODES; i += 256) {
            float t = TBL_LO + (float)i * TBL_STEP;
            node[i] = net_eval(t, w1, b1, w2, b2, w30, b30, w31, b31);
        }
    }
    __syncthreads();
    for (int i = threadIdx.x; i < TBL_N; i += 256) {
        f16x2 p;
        p.x = (_Float16)node[i];
        p.y = (_Float16)node[i + 1];
        lut[i] = __builtin_bit_cast(unsigned, p);
    }
    __syncthreads();

    const float A = (*cw_p) * TBL_SCALE;
    const float B = ((*cb_p) - TBL_LO) * TBL_SCALE;
    const float UMAX = (float)TBL_N - 0.001f;

#define LERP(dst, xin)                                                  \
    do {                                                                \
        float u = fmaf((xin), A, B);                                    \
        u = fminf(fmaxf(u, 0.0f), UMAX);                                \
        int   i_ = (int)u;                                              \
        float fr = u - (float)i_;                                       \
        f16x2 p_ = __builtin_bit_cast(f16x2, lut[i_]);                  \
        float f0 = (float)p_.x, f1 = (float)p_.y;                       \
        (dst) = fmaf(fr, f1 - f0, f0);                                  \
    } while (0)

    if (full) {
        // group 0 from the hoisted registers
#pragma unroll
        for (int k = 0; k < 4; ++k) {
            f32x4 r;
#pragma unroll
            for (int j = 0; j < 4; ++j) LERP(r[j], v0[k][j]);
            out4[base + k * 256] = r;
        }
        // groups 1..3: load 4, process 4 — no bounds guards
#pragma unroll
        for (int kk = 1; kk < 4; ++kk) {
            f32x4 v[4];
#pragma unroll
            for (int k = 0; k < 4; ++k) v[k] = data4[base + (kk * 4 + k) * 256];
#pragma unroll
            for (int k = 0; k < 4; ++k) {
                f32x4 r;
#pragma unroll
                for (int j = 0; j < 4; ++j) LERP(r[j], v[k][j]);
                out4[base + (kk * 4 + k) * 256] = r;
            }
        }
    } else {
        // tail block (not hit at N=33.5M): fully guarded
        for (int kk = 0; kk < 16; ++kk) {
            int idx = base + kk * 256;
            if (idx < n4) {
                f32x4 v = (kk < 4) ? v0[kk] : data4[idx];
                f32x4 r;
#pragma unroll
                for (int j = 0; j < 4; ++j) LERP(r[j], v[j]);
                out4[idx] = r;
            }
        }
    }
#undef LERP
}

extern "C" void kernel_launch(void* const* d_in, const int* in_sizes, int n_in,
                              void* d_out, int out_size, void* d_ws, size_t ws_size,
                              hipStream_t stream) {
    const float* data = (const float*)d_in[0];
    const float* cw   = (const float*)d_in[1];
    const float* cb   = (const float*)d_in[2];
    const float* w1   = (const float*)d_in[3];
    const float* b1   = (const float*)d_in[4];
    const float* w2   = (const float*)d_in[5];
    const float* b2   = (const float*)d_in[6];
    const float* w3   = (const float*)d_in[7];
    const float* b3   = (const float*)d_in[8];
    float* out = (float*)d_out;

    const int n  = in_sizes[0];       // 33,554,432
    const int n4 = n / 4;             // 8,388,608 float4s

    const int block = 256;
    const int per_block = block * 16;                  // 4096 float4s per block
    const int grid = (n4 + per_block - 1) / per_block; // 2048 (= 8 blocks/CU)

    hybridconv_lut_kernel<<<grid, block, 0, stream>>>(
        (const f32x4*)data, (f32x4*)out,
        cw, cb, w1, b1, w2, b2, w3, b3, n4);
}